// Round 8
// baseline (182.066 us; speedup 1.0000x reference)
//
#include <hip/hip_runtime.h>
#include <hip/hip_bf16.h>
#include <stdint.h>

#define B_ 2
#define C_ 256
#define H_ 192
#define W_ 192
#define HW_ (H_*W_)
#define CHW_ (C_*HW_)
#define P_ (B_*HW_)
#define SCALE 0.125f

typedef __attribute__((ext_vector_type(8))) short bf16x8;
typedef __attribute__((ext_vector_type(4))) float f32x4;
typedef __attribute__((ext_vector_type(16))) float f32x16;

__device__ __forceinline__ void gload_lds16(const void* g, void* l) {
  __builtin_amdgcn_global_load_lds(
      (const __attribute__((address_space(1))) uint32_t*)g,
      (__attribute__((address_space(3))) uint32_t*)l, 16, 0, 0);
}

// ---- weights: w15/w51 [co][ci][k] fp32 -> bf16 [co][k*256+ci]; w11 appended; zero zbuf
__global__ __launch_bounds__(256) void wtrans_kernel(
    const float* __restrict__ w15, const float* __restrict__ w51,
    const float* __restrict__ w11,
    __hip_bfloat16* __restrict__ w1t, __hip_bfloat16* __restrict__ w2t,
    __hip_bfloat16* __restrict__ zbuf) {
  int i = blockIdx.x * 256 + threadIdx.x;
  if (i < C_ * C_ * 5) {
    int co = i / (C_ * 5);
    int r  = i - co * (C_ * 5);
    int ci = r / 5;
    int k  = r - ci * 5;
    w1t[(size_t)co * 1280 + k * 256 + ci] = __float2bfloat16(w15[i]);
    w2t[(size_t)co * 1536 + k * 256 + ci] = __float2bfloat16(w51[i]);
  }
  if (i < C_ * C_) {
    int co = i >> 8, ci = i & 255;
    w2t[(size_t)co * 1536 + 1280 + ci] = __float2bfloat16(w11[i]);
  }
  if (i < 1024) zbuf[i] = __float2bfloat16(0.f);
}

// ---- x NCHW fp32 -> xT NHWC bf16 (LDS 32x32 tile transpose)
__global__ __launch_bounds__(256) void nchw2nhwc_kernel(
    const float* __restrict__ x, __hip_bfloat16* __restrict__ xT) {
  __shared__ float tile[32][33];
  int p0 = blockIdx.x * 32, c0 = blockIdx.y * 32, b = blockIdx.z;
  int tx = threadIdx.x, ty = threadIdx.y;
  const float* xb = x + (size_t)b * CHW_;
#pragma unroll
  for (int j = 0; j < 4; ++j)
    tile[ty + j * 8][tx] = xb[(size_t)(c0 + ty + j * 8) * HW_ + p0 + tx];
  __syncthreads();
  __hip_bfloat16* xo = xT + (size_t)b * HW_ * C_;
#pragma unroll
  for (int j = 0; j < 4; ++j)
    xo[(size_t)(p0 + ty + j * 8) * C_ + c0 + tx] = __float2bfloat16(tile[tx][ty + j * 8]);
}

// ---- GEMM1 (frozen): t1[p][co] = bf16(conv1x5(xT)+b15). Tile = one h-row x 128 co.
#define AB1 25600  // A = 200 rows * 128B
__global__ __launch_bounds__(256, 3) void gemm1_kernel(
    const __hip_bfloat16* __restrict__ xT, const __hip_bfloat16* __restrict__ w1t,
    const float* __restrict__ b15, __hip_bfloat16* __restrict__ t1,
    const __hip_bfloat16* __restrict__ zbuf) {
  __shared__ __align__(16) char lds[AB1 + 16384];
  int bid = blockIdx.x;
  bid = (bid & 7) * 96 + (bid >> 3);  // XCD swizzle (768 % 8 == 0)
  const int nb = bid & 1, bh = bid >> 1;
  const int p0 = bh * 192;
  const int tid = threadIdx.x, l = tid & 63, wid = tid >> 6;
  const int wrow = (wid >> 1) * 96, wcol = (wid & 1) * 64;
  const int sboff = (((l & 7) ^ (l >> 3)) << 4);
  const int lrow = l >> 3;
  const int corow0 = nb * 128;

  int b_ad[4][2];
#pragma unroll
  for (int n = 0; n < 4; ++n)
#pragma unroll
    for (int kk = 0; kk < 2; ++kk)
      b_ad[n][kk] = AB1 + (wcol + n * 16 + (l & 15)) * 128 +
                    (((kk * 4 + (l >> 4)) ^ ((l & 15) & 7)) << 4);

  f32x4 acc[6][4] = {};
  const char* xTb = (const char*)xT;
  const char* wB  = (const char*)w1t;
  const char* zb  = (const char*)zbuf;

  for (int cib = 0; cib < 4; ++cib) {
    for (int is = wid; is < 25; is += 4) {
      int row = is * 8 + lrow;
      const char* src = ((unsigned)(row - 4) < 192u)
          ? xTb + (size_t)(p0 + row - 4) * 512 + cib * 128 + sboff
          : zb + sboff;
      gload_lds16(src, lds + is * 1024);
    }
    for (int k = 0; k < 5; ++k) {
      int boff = k * 512 + cib * 128;
#pragma unroll
      for (int ii = 0; ii < 4; ++ii) {
        int is = wid * 4 + ii;
        const char* bs = wB + (size_t)(corow0 + is * 8 + lrow) * 2560 + boff + sboff;
        gload_lds16(bs, lds + AB1 + is * 1024);
      }
      __syncthreads();
      int x8 = ((l & 15) + k + 2) & 7;
      int arow0 = wrow + (l & 15) + k + 2;
#pragma unroll
      for (int kk = 0; kk < 2; ++kk) {
        int ablk = ((kk * 4 + (l >> 4)) ^ x8) << 4;
        bf16x8 bfr[4];
#pragma unroll
        for (int n = 0; n < 4; ++n) bfr[n] = *(const bf16x8*)(lds + b_ad[n][kk]);
#pragma unroll
        for (int m = 0; m < 6; ++m) {
          bf16x8 af = *(const bf16x8*)(lds + (arow0 + m * 16) * 128 + ablk);
#pragma unroll
          for (int n = 0; n < 4; ++n)
            acc[m][n] = __builtin_amdgcn_mfma_f32_16x16x32_bf16(af, bfr[n], acc[m][n], 0, 0, 0);
        }
      }
      __syncthreads();
    }
  }
#pragma unroll
  for (int n = 0; n < 4; ++n) {
    int co = corow0 + wcol + n * 16 + (l & 15);
    float bias = b15[co];
#pragma unroll
    for (int m = 0; m < 6; ++m) {
      int prow = p0 + wrow + m * 16 + (l >> 4) * 4;
#pragma unroll
      for (int r = 0; r < 4; ++r)
        t1[(size_t)(prow + r) * 256 + co] = __float2bfloat16(acc[m][n][r] + bias);
    }
  }
}

// ---- GEMM2 (NEW): 32x32x16 MFMA, 96x64 wave tile, counted-vmcnt dbuf pipeline.
// BM=192 x BN=128, BK=64, 256 thr (4 waves 2x2). LDS 80 KB -> 2 blocks/CU.
#define A2SZ 24576
#define B2OFF 49152
__global__ __launch_bounds__(256, 2) void gemm2_kernel(
    const __hip_bfloat16* __restrict__ t1, const __hip_bfloat16* __restrict__ xT,
    const __hip_bfloat16* __restrict__ w2t,
    const float* __restrict__ b51, const float* __restrict__ b11,
    __hip_bfloat16* __restrict__ featT, const __hip_bfloat16* __restrict__ zbuf) {
  __shared__ __align__(16) char lds[81920];
  int bid = blockIdx.x;
  bid = (bid & 7) * 96 + (bid >> 3);  // XCD swizzle (768 % 8 == 0)
  const int nb = bid & 1, bh = bid >> 1;
  const int p0 = bh * 192;
  const int h = bh % 192;
  const int tid = threadIdx.x, l = tid & 63, wid = tid >> 6;
  const int wrow = (wid >> 1) * 96, wcol = (wid & 1) * 64;
  const int sboff = (((l & 7) ^ (l >> 3)) << 4);
  const int lrow = l >> 3;
  const int corow0 = nb * 128;

  const char* t1b = (const char*)t1;
  const char* xTb = (const char*)xT;
  const char* wB  = (const char*)w2t;
  const char* zb  = (const char*)zbuf;

  // A tile 192 rows x 128B = 24 slots x 1KB; 6 issues/thread (4 waves)
  auto stageA = [&](int s, int buf) {
    const char* abase;
    if (s < 20) {
      int k = s >> 2, cib = s & 3, dl = k - 2;
      abase = ((unsigned)(h + dl) < 192u)
          ? t1b + (size_t)(p0 + dl * 192) * 512 + cib * 128
          : (const char*)0;
    } else {
      abase = xTb + (size_t)p0 * 512 + (s - 20) * 128;
    }
#pragma unroll
    for (int i = 0; i < 6; ++i) {
      int slot = i * 4 + wid;
      int row = slot * 8 + lrow;
      const char* src = abase ? abase + (size_t)row * 512 + sboff : zb + sboff;
      gload_lds16(src, lds + buf * A2SZ + slot * 1024);
    }
  };
  // B tile 128 co x 128B = 16 slots; 4 issues/thread
  auto stageB = [&](int s, int buf) {
    int boff = (s < 20) ? (s >> 2) * 512 + (s & 3) * 128 : 2560 + (s - 20) * 128;
#pragma unroll
    for (int i = 0; i < 4; ++i) {
      int slot = i * 4 + wid;
      const char* bs = wB + (size_t)(corow0 + slot * 8 + lrow) * 3072 + boff + sboff;
      gload_lds16(bs, lds + B2OFF + buf * 16384 + slot * 1024);
    }
  };

  // ds_read addresses (constant; only buf base changes). row&7 == col&7 == l&7.
  int a_ad[3][4], b_ad[2][4];
#pragma unroll
  for (int m = 0; m < 3; ++m)
#pragma unroll
    for (int k2 = 0; k2 < 4; ++k2)
      a_ad[m][k2] = (wrow + m * 32 + (l & 31)) * 128 +
                    (((k2 * 2 + (l >> 5)) ^ (l & 7)) << 4);
#pragma unroll
  for (int n = 0; n < 2; ++n)
#pragma unroll
    for (int k2 = 0; k2 < 4; ++k2)
      b_ad[n][k2] = B2OFF + (wcol + n * 32 + (l & 31)) * 128 +
                    (((k2 * 2 + (l >> 5)) ^ (l & 7)) << 4);

  f32x16 acc[3][2] = {};
  stageA(0, 0);
  stageB(0, 0);
  for (int t = 0; t < 24; ++t) {
    const int cur = t & 1, nxt = cur ^ 1;
    if (t < 23) {
      stageA(t + 1, nxt);                               // 6 loads stay in flight
      asm volatile("s_waitcnt vmcnt(6)" ::: "memory");  // tile t's 10 done
    } else {
      asm volatile("s_waitcnt vmcnt(0)" ::: "memory");
    }
    __builtin_amdgcn_s_barrier();
    __builtin_amdgcn_sched_barrier(0);
    const int ab = cur * A2SZ, bb = cur * 16384;
#pragma unroll
    for (int k2 = 0; k2 < 2; ++k2) {
      bf16x8 af[3], bfr[2];
#pragma unroll
      for (int m = 0; m < 3; ++m) af[m] = *(const bf16x8*)(lds + ab + a_ad[m][k2]);
#pragma unroll
      for (int n = 0; n < 2; ++n) bfr[n] = *(const bf16x8*)(lds + bb + b_ad[n][k2]);
      __builtin_amdgcn_s_setprio(1);
#pragma unroll
      for (int m = 0; m < 3; ++m)
#pragma unroll
        for (int n = 0; n < 2; ++n)
          acc[m][n] = __builtin_amdgcn_mfma_f32_32x32x16_bf16(af[m], bfr[n], acc[m][n], 0, 0, 0);
      __builtin_amdgcn_s_setprio(0);
    }
    if (t < 23) stageB(t + 1, nxt);                     // 4 more for tile t+1
#pragma unroll
    for (int k2 = 2; k2 < 4; ++k2) {
      bf16x8 af[3], bfr[2];
#pragma unroll
      for (int m = 0; m < 3; ++m) af[m] = *(const bf16x8*)(lds + ab + a_ad[m][k2]);
#pragma unroll
      for (int n = 0; n < 2; ++n) bfr[n] = *(const bf16x8*)(lds + bb + b_ad[n][k2]);
      __builtin_amdgcn_s_setprio(1);
#pragma unroll
      for (int m = 0; m < 3; ++m)
#pragma unroll
        for (int n = 0; n < 2; ++n)
          acc[m][n] = __builtin_amdgcn_mfma_f32_32x32x16_bf16(af[m], bfr[n], acc[m][n], 0, 0, 0);
      __builtin_amdgcn_s_setprio(0);
    }
    __builtin_amdgcn_sched_barrier(0);
    __builtin_amdgcn_s_barrier();
    __builtin_amdgcn_sched_barrier(0);
  }
  // C/D: col = lane&31, row = (reg&3) + 8*(reg>>2) + 4*(lane>>5)   [m74/m101]
#pragma unroll
  for (int n = 0; n < 2; ++n) {
    int co = corow0 + wcol + n * 32 + (l & 31);
    float bias = b51[co] + b11[co];
#pragma unroll
    for (int m = 0; m < 3; ++m) {
      int prow0 = p0 + wrow + m * 32 + 4 * (l >> 5);
#pragma unroll
      for (int r = 0; r < 16; ++r) {
        int prow = prow0 + (r & 3) + 8 * (r >> 2);
        featT[(size_t)prow * 256 + co] = __float2bfloat16(acc[m][n][r] + bias);
      }
    }
  }
}

// ---- out = x + feat + bilinear_gather(feat)  (frozen)
__global__ __launch_bounds__(256) void align_kernel(
    const __hip_bfloat16* __restrict__ xT, const __hip_bfloat16* __restrict__ featT,
    const float* __restrict__ boxes, float* __restrict__ out) {
  __shared__ float vs[32][258];
  const int tid = threadIdx.x, l = tid & 63, wv = tid >> 6;
  const int p0 = blockIdx.x * 32;

#pragma unroll 4
  for (int i = 0; i < 8; ++i) {
    int pl = wv * 8 + i;
    int p = p0 + pl;
    int b = p / HW_;
    int p2 = p - b * HW_;
    float yy = boxes[(size_t)p * 5 + 0] * SCALE;
    float xx = boxes[(size_t)p * 5 + 1] * SCALE;
    bool valid = (yy >= -1.0f) && (yy <= (float)H_) && (xx >= -1.0f) && (xx <= (float)W_);
    yy = fmaxf(yy, 0.f);
    xx = fmaxf(xx, 0.f);
    int yl = (int)floorf(yy), xl = (int)floorf(xx);
    int yh, xh;
    if (yl >= H_ - 1) { yl = H_ - 1; yh = H_ - 1; yy = (float)(H_ - 1); } else { yh = yl + 1; }
    if (xl >= W_ - 1) { xl = W_ - 1; xh = W_ - 1; xx = (float)(W_ - 1); } else { xh = xl + 1; }
    float ly = yy - (float)yl, lx = xx - (float)xl;
    float hy = 1.f - ly, hx = 1.f - lx;
    float q00 = hy * hx, q01 = hy * lx, q10 = ly * hx, q11 = ly * lx;
    if (!valid) { q00 = 0.f; q01 = 0.f; q10 = 0.f; q11 = 0.f; }
    const unsigned short* fT = (const unsigned short*)featT + (size_t)b * HW_ * C_;
    const unsigned short* xb = (const unsigned short*)xT + (size_t)b * HW_ * C_;
    int co = l * 4;
    uint2 A  = *(const uint2*)(fT + ((size_t)yl * W_ + xl) * C_ + co);
    uint2 Bv = *(const uint2*)(fT + ((size_t)yl * W_ + xh) * C_ + co);
    uint2 Cv = *(const uint2*)(fT + ((size_t)yh * W_ + xl) * C_ + co);
    uint2 D  = *(const uint2*)(fT + ((size_t)yh * W_ + xh) * C_ + co);
    uint2 E  = *(const uint2*)(fT + (size_t)p2 * C_ + co);
    uint2 X  = *(const uint2*)(xb + (size_t)p2 * C_ + co);
    float o[4];
#pragma unroll
    for (int w = 0; w < 2; ++w) {
      unsigned int aw = (&A.x)[w], bw = (&Bv.x)[w], cw = (&Cv.x)[w],
                   dw = (&D.x)[w], ew = (&E.x)[w], xw = (&X.x)[w];
      float a0 = __uint_as_float(aw << 16), a1 = __uint_as_float(aw & 0xffff0000u);
      float b0 = __uint_as_float(bw << 16), b1 = __uint_as_float(bw & 0xffff0000u);
      float c0 = __uint_as_float(cw << 16), c1 = __uint_as_float(cw & 0xffff0000u);
      float d0 = __uint_as_float(dw << 16), d1 = __uint_as_float(dw & 0xffff0000u);
      float e0 = __uint_as_float(ew << 16), e1 = __uint_as_float(ew & 0xffff0000u);
      float x0 = __uint_as_float(xw << 16), x1 = __uint_as_float(xw & 0xffff0000u);
      o[w * 2 + 0] = x0 + e0 + q00 * a0 + q01 * b0 + q10 * c0 + q11 * d0;
      o[w * 2 + 1] = x1 + e1 + q00 * a1 + q01 * b1 + q10 * c1 + q11 * d1;
    }
    *(float2*)&vs[pl][co]     = make_float2(o[0], o[1]);
    *(float2*)&vs[pl][co + 2] = make_float2(o[2], o[3]);
  }
  __syncthreads();

  const int pl = tid & 31, cg = tid >> 5;
  const int p = p0 + pl;
  const int b = p / HW_;
  const int p2 = p - b * HW_;
  float* oc = out + (size_t)b * CHW_ + p2;
#pragma unroll
  for (int j = 0; j < 32; ++j) {
    int ch = cg * 32 + j;
    __builtin_nontemporal_store(vs[pl][ch], &oc[(size_t)ch * HW_]);
  }
}

extern "C" void kernel_launch(void* const* d_in, const int* in_sizes, int n_in,
                              void* d_out, int out_size, void* d_ws, size_t ws_size,
                              hipStream_t stream) {
  const float* x     = (const float*)d_in[0];
  const float* boxes = (const float*)d_in[1];
  const float* w51   = (const float*)d_in[2];
  const float* b51   = (const float*)d_in[3];
  const float* w15   = (const float*)d_in[4];
  const float* b15   = (const float*)d_in[5];
  const float* w11   = (const float*)d_in[6];
  const float* b11   = (const float*)d_in[7];
  float* out = (float*)d_out;

  __hip_bfloat16* featT = (__hip_bfloat16*)d_ws;
  __hip_bfloat16* xT   = featT + (size_t)P_ * C_;
  __hip_bfloat16* w1t  = xT + (size_t)P_ * C_;
  __hip_bfloat16* w2t  = w1t + (size_t)C_ * 1280;
  __hip_bfloat16* zbuf = w2t + (size_t)C_ * 1536;
  __hip_bfloat16* t1 = (__hip_bfloat16*)d_out;

  wtrans_kernel<<<dim3((C_ * C_ * 5 + 255) / 256), 256, 0, stream>>>(
      w15, w51, w11, w1t, w2t, zbuf);
  nchw2nhwc_kernel<<<dim3(HW_ / 32, C_ / 32, B_), dim3(32, 8), 0, stream>>>(x, xT);
  gemm1_kernel<<<dim3(768), 256, 0, stream>>>(xT, w1t, b15, t1, zbuf);
  gemm2_kernel<<<dim3(768), 256, 0, stream>>>(t1, xT, w2t, b51, b11, featT, zbuf);
  align_kernel<<<dim3(P_ / 32), 256, 0, stream>>>(xT, featT, boxes, out);
}

// Round 9
// 172.690 us; speedup vs baseline: 1.0543x; 1.0543x over previous
//
#include <hip/hip_runtime.h>
#include <hip/hip_bf16.h>
#include <stdint.h>

#define B_ 2
#define C_ 256
#define H_ 192
#define W_ 192
#define HW_ (H_*W_)
#define CHW_ (C_*HW_)
#define P_ (B_*HW_)
#define SCALE 0.125f

typedef __attribute__((ext_vector_type(8))) short bf16x8;
typedef __attribute__((ext_vector_type(4))) float f32x4;

__device__ __forceinline__ void gload_lds16(const void* g, void* l) {
  __builtin_amdgcn_global_load_lds(
      (const __attribute__((address_space(1))) uint32_t*)g,
      (__attribute__((address_space(3))) uint32_t*)l, 16, 0, 0);
}

// ---- weights: w15/w51 [co][ci][k] fp32 -> bf16 [co][k*256+ci]; w11 appended; zero zbuf
__global__ __launch_bounds__(256) void wtrans_kernel(
    const float* __restrict__ w15, const float* __restrict__ w51,
    const float* __restrict__ w11,
    __hip_bfloat16* __restrict__ w1t, __hip_bfloat16* __restrict__ w2t,
    __hip_bfloat16* __restrict__ zbuf) {
  int i = blockIdx.x * 256 + threadIdx.x;
  if (i < C_ * C_ * 5) {
    int co = i / (C_ * 5);
    int r  = i - co * (C_ * 5);
    int ci = r / 5;
    int k  = r - ci * 5;
    w1t[(size_t)co * 1280 + k * 256 + ci] = __float2bfloat16(w15[i]);
    w2t[(size_t)co * 1536 + k * 256 + ci] = __float2bfloat16(w51[i]);
  }
  if (i < C_ * C_) {
    int co = i >> 8, ci = i & 255;
    w2t[(size_t)co * 1536 + 1280 + ci] = __float2bfloat16(w11[i]);
  }
  if (i < 1024) zbuf[i] = __float2bfloat16(0.f);
}

// ---- x NCHW fp32 -> xT NHWC bf16 (LDS 32x32 tile transpose)
__global__ __launch_bounds__(256) void nchw2nhwc_kernel(
    const float* __restrict__ x, __hip_bfloat16* __restrict__ xT) {
  __shared__ float tile[32][33];
  int p0 = blockIdx.x * 32, c0 = blockIdx.y * 32, b = blockIdx.z;
  int tx = threadIdx.x, ty = threadIdx.y;
  const float* xb = x + (size_t)b * CHW_;
#pragma unroll
  for (int j = 0; j < 4; ++j)
    tile[ty + j * 8][tx] = xb[(size_t)(c0 + ty + j * 8) * HW_ + p0 + tx];
  __syncthreads();
  __hip_bfloat16* xo = xT + (size_t)b * HW_ * C_;
#pragma unroll
  for (int j = 0; j < 4; ++j)
    xo[(size_t)(p0 + ty + j * 8) * C_ + c0 + tx] = __float2bfloat16(tile[tx][ty + j * 8]);
}

// ---- GEMM1 (frozen): t1[p][co] = bf16(conv1x5(xT)+b15). Tile = one h-row x 128 co.
#define AB1 25600  // A = 200 rows * 128B
__global__ __launch_bounds__(256, 3) void gemm1_kernel(
    const __hip_bfloat16* __restrict__ xT, const __hip_bfloat16* __restrict__ w1t,
    const float* __restrict__ b15, __hip_bfloat16* __restrict__ t1,
    const __hip_bfloat16* __restrict__ zbuf) {
  __shared__ __align__(16) char lds[AB1 + 16384];
  int bid = blockIdx.x;
  bid = (bid & 7) * 96 + (bid >> 3);  // XCD swizzle (768 % 8 == 0)
  const int nb = bid & 1, bh = bid >> 1;
  const int p0 = bh * 192;
  const int tid = threadIdx.x, l = tid & 63, wid = tid >> 6;
  const int wrow = (wid >> 1) * 96, wcol = (wid & 1) * 64;
  const int sboff = (((l & 7) ^ (l >> 3)) << 4);
  const int lrow = l >> 3;
  const int corow0 = nb * 128;

  int b_ad[4][2];
#pragma unroll
  for (int n = 0; n < 4; ++n)
#pragma unroll
    for (int kk = 0; kk < 2; ++kk)
      b_ad[n][kk] = AB1 + (wcol + n * 16 + (l & 15)) * 128 +
                    (((kk * 4 + (l >> 4)) ^ ((l & 15) & 7)) << 4);

  f32x4 acc[6][4] = {};
  const char* xTb = (const char*)xT;
  const char* wB  = (const char*)w1t;
  const char* zb  = (const char*)zbuf;

  for (int cib = 0; cib < 4; ++cib) {
    for (int is = wid; is < 25; is += 4) {
      int row = is * 8 + lrow;
      const char* src = ((unsigned)(row - 4) < 192u)
          ? xTb + (size_t)(p0 + row - 4) * 512 + cib * 128 + sboff
          : zb + sboff;
      gload_lds16(src, lds + is * 1024);
    }
    for (int k = 0; k < 5; ++k) {
      int boff = k * 512 + cib * 128;
#pragma unroll
      for (int ii = 0; ii < 4; ++ii) {
        int is = wid * 4 + ii;
        const char* bs = wB + (size_t)(corow0 + is * 8 + lrow) * 2560 + boff + sboff;
        gload_lds16(bs, lds + AB1 + is * 1024);
      }
      __syncthreads();
      int x8 = ((l & 15) + k + 2) & 7;
      int arow0 = wrow + (l & 15) + k + 2;
#pragma unroll
      for (int kk = 0; kk < 2; ++kk) {
        int ablk = ((kk * 4 + (l >> 4)) ^ x8) << 4;
        bf16x8 bfr[4];
#pragma unroll
        for (int n = 0; n < 4; ++n) bfr[n] = *(const bf16x8*)(lds + b_ad[n][kk]);
#pragma unroll
        for (int m = 0; m < 6; ++m) {
          bf16x8 af = *(const bf16x8*)(lds + (arow0 + m * 16) * 128 + ablk);
#pragma unroll
          for (int n = 0; n < 4; ++n)
            acc[m][n] = __builtin_amdgcn_mfma_f32_16x16x32_bf16(af, bfr[n], acc[m][n], 0, 0, 0);
        }
      }
      __syncthreads();
    }
  }
#pragma unroll
  for (int n = 0; n < 4; ++n) {
    int co = corow0 + wcol + n * 16 + (l & 15);
    float bias = b15[co];
#pragma unroll
    for (int m = 0; m < 6; ++m) {
      int prow = p0 + wrow + m * 16 + (l >> 4) * 4;
#pragma unroll
      for (int r = 0; r < 4; ++r)
        t1[(size_t)(prow + r) * 256 + co] = __float2bfloat16(acc[m][n][r] + bias);
    }
  }
}

// ---- GEMM2 (reverted to R5 winner): 16x16x32, 96x64 wave tile, 2-barrier loop.
#define AB2 24576  // A = 192 rows * 128B
__global__ __launch_bounds__(256, 3) void gemm2_kernel(
    const __hip_bfloat16* __restrict__ t1, const __hip_bfloat16* __restrict__ xT,
    const __hip_bfloat16* __restrict__ w2t,
    const float* __restrict__ b51, const float* __restrict__ b11,
    __hip_bfloat16* __restrict__ featT, const __hip_bfloat16* __restrict__ zbuf) {
  __shared__ __align__(16) char lds[AB2 + 16384];
  int bid = blockIdx.x;
  bid = (bid & 7) * 96 + (bid >> 3);
  const int nb = bid & 1, bh = bid >> 1;
  const int p0 = bh * 192;
  const int h = bh % 192;
  const int tid = threadIdx.x, l = tid & 63, wid = tid >> 6;
  const int wrow = (wid >> 1) * 96, wcol = (wid & 1) * 64;
  const int sboff = (((l & 7) ^ (l >> 3)) << 4);
  const int lrow = l >> 3;
  const int corow0 = nb * 128;

  int a_ad[6][2], b_ad[4][2];
#pragma unroll
  for (int m = 0; m < 6; ++m)
#pragma unroll
    for (int kk = 0; kk < 2; ++kk)
      a_ad[m][kk] = (wrow + m * 16 + (l & 15)) * 128 +
                    (((kk * 4 + (l >> 4)) ^ ((l & 15) & 7)) << 4);
#pragma unroll
  for (int n = 0; n < 4; ++n)
#pragma unroll
    for (int kk = 0; kk < 2; ++kk)
      b_ad[n][kk] = AB2 + (wcol + n * 16 + (l & 15)) * 128 +
                    (((kk * 4 + (l >> 4)) ^ ((l & 15) & 7)) << 4);

  f32x4 acc[6][4] = {};
  const char* t1b = (const char*)t1;
  const char* xTb = (const char*)xT;
  const char* wB  = (const char*)w2t;
  const char* zb  = (const char*)zbuf;

  for (int s = 0; s < 24; ++s) {
    const char* abase;
    int boff;
    if (s < 20) {
      int k = s >> 2, cib = s & 3, dl = k - 2;
      abase = ((unsigned)(h + dl) < 192u)
          ? t1b + (size_t)(p0 + dl * 192) * 512 + cib * 128
          : (const char*)0;
      boff = k * 512 + cib * 128;
    } else {
      abase = xTb + (size_t)p0 * 512 + (s - 20) * 128;
      boff = 2560 + (s - 20) * 128;
    }
    for (int is = wid; is < 24; is += 4) {
      int row = is * 8 + lrow;
      const char* src = abase ? abase + (size_t)row * 512 + sboff : zb + sboff;
      gload_lds16(src, lds + is * 1024);
    }
#pragma unroll
    for (int ii = 0; ii < 4; ++ii) {
      int is = wid * 4 + ii;
      const char* bs = wB + (size_t)(corow0 + is * 8 + lrow) * 3072 + boff + sboff;
      gload_lds16(bs, lds + AB2 + is * 1024);
    }
    __syncthreads();
#pragma unroll
    for (int kk = 0; kk < 2; ++kk) {
      bf16x8 bfr[4];
#pragma unroll
      for (int n = 0; n < 4; ++n) bfr[n] = *(const bf16x8*)(lds + b_ad[n][kk]);
#pragma unroll
      for (int m = 0; m < 6; ++m) {
        bf16x8 af = *(const bf16x8*)(lds + a_ad[m][kk]);
#pragma unroll
        for (int n = 0; n < 4; ++n)
          acc[m][n] = __builtin_amdgcn_mfma_f32_16x16x32_bf16(af, bfr[n], acc[m][n], 0, 0, 0);
      }
    }
    __syncthreads();
  }
#pragma unroll
  for (int n = 0; n < 4; ++n) {
    int co = corow0 + wcol + n * 16 + (l & 15);
    float bias = b51[co] + b11[co];
#pragma unroll
    for (int m = 0; m < 6; ++m) {
      int prow = p0 + wrow + m * 16 + (l >> 4) * 4;
#pragma unroll
      for (int r = 0; r < 4; ++r)
        featT[(size_t)(prow + r) * 256 + co] = __float2bfloat16(acc[m][n][r] + bias);
    }
  }
}

// ---- out = x + feat + bilinear_gather(feat).
// NEW: 16 pixels/block (grid 4608, LDS 16.5KB) -> ~2x blocks/CU, 2x gather
// streams in flight. Phase A: lane=channel, 512B fully-consumed corner loads.
// Phase B: lane=pixel, coalesced NCHW NT stores.
__global__ __launch_bounds__(256) void align_kernel(
    const __hip_bfloat16* __restrict__ xT, const __hip_bfloat16* __restrict__ featT,
    const float* __restrict__ boxes, float* __restrict__ out) {
  __shared__ float vs[16][258];  // [pixel][channel], +2 pad
  const int tid = threadIdx.x, l = tid & 63, wv = tid >> 6;
  const int p0 = blockIdx.x * 16;

#pragma unroll
  for (int i = 0; i < 4; ++i) {
    int pl = wv * 4 + i;
    int p = p0 + pl;
    int b = p / HW_;
    int p2 = p - b * HW_;
    float yy = boxes[(size_t)p * 5 + 0] * SCALE;
    float xx = boxes[(size_t)p * 5 + 1] * SCALE;
    bool valid = (yy >= -1.0f) && (yy <= (float)H_) && (xx >= -1.0f) && (xx <= (float)W_);
    yy = fmaxf(yy, 0.f);
    xx = fmaxf(xx, 0.f);
    int yl = (int)floorf(yy), xl = (int)floorf(xx);
    int yh, xh;
    if (yl >= H_ - 1) { yl = H_ - 1; yh = H_ - 1; yy = (float)(H_ - 1); } else { yh = yl + 1; }
    if (xl >= W_ - 1) { xl = W_ - 1; xh = W_ - 1; xx = (float)(W_ - 1); } else { xh = xl + 1; }
    float ly = yy - (float)yl, lx = xx - (float)xl;
    float hy = 1.f - ly, hx = 1.f - lx;
    float q00 = hy * hx, q01 = hy * lx, q10 = ly * hx, q11 = ly * lx;
    if (!valid) { q00 = 0.f; q01 = 0.f; q10 = 0.f; q11 = 0.f; }
    const unsigned short* fT = (const unsigned short*)featT + (size_t)b * HW_ * C_;
    const unsigned short* xb = (const unsigned short*)xT + (size_t)b * HW_ * C_;
    int co = l * 4;
    uint2 A  = *(const uint2*)(fT + ((size_t)yl * W_ + xl) * C_ + co);
    uint2 Bv = *(const uint2*)(fT + ((size_t)yl * W_ + xh) * C_ + co);
    uint2 Cv = *(const uint2*)(fT + ((size_t)yh * W_ + xl) * C_ + co);
    uint2 D  = *(const uint2*)(fT + ((size_t)yh * W_ + xh) * C_ + co);
    uint2 E  = *(const uint2*)(fT + (size_t)p2 * C_ + co);
    uint2 X  = *(const uint2*)(xb + (size_t)p2 * C_ + co);
    float o[4];
#pragma unroll
    for (int w = 0; w < 2; ++w) {
      unsigned int aw = (&A.x)[w], bw = (&Bv.x)[w], cw = (&Cv.x)[w],
                   dw = (&D.x)[w], ew = (&E.x)[w], xw = (&X.x)[w];
      float a0 = __uint_as_float(aw << 16), a1 = __uint_as_float(aw & 0xffff0000u);
      float b0 = __uint_as_float(bw << 16), b1 = __uint_as_float(bw & 0xffff0000u);
      float c0 = __uint_as_float(cw << 16), c1 = __uint_as_float(cw & 0xffff0000u);
      float d0 = __uint_as_float(dw << 16), d1 = __uint_as_float(dw & 0xffff0000u);
      float e0 = __uint_as_float(ew << 16), e1 = __uint_as_float(ew & 0xffff0000u);
      float x0 = __uint_as_float(xw << 16), x1 = __uint_as_float(xw & 0xffff0000u);
      o[w * 2 + 0] = x0 + e0 + q00 * a0 + q01 * b0 + q10 * c0 + q11 * d0;
      o[w * 2 + 1] = x1 + e1 + q00 * a1 + q01 * b1 + q10 * c1 + q11 * d1;
    }
    *(float2*)&vs[pl][co]     = make_float2(o[0], o[1]);
    *(float2*)&vs[pl][co + 2] = make_float2(o[2], o[3]);
  }
  __syncthreads();

  // Phase B: lane=pixel (16 px), 16 ch-groups of 16
  const int pl = tid & 15, cg = tid >> 4;
  const int p = p0 + pl;
  const int b = p / HW_;
  const int p2 = p - b * HW_;
  float* oc = out + (size_t)b * CHW_ + p2;
#pragma unroll
  for (int j = 0; j < 16; ++j) {
    int ch = cg * 16 + j;
    __builtin_nontemporal_store(vs[pl][ch], &oc[(size_t)ch * HW_]);
  }
}

extern "C" void kernel_launch(void* const* d_in, const int* in_sizes, int n_in,
                              void* d_out, int out_size, void* d_ws, size_t ws_size,
                              hipStream_t stream) {
  const float* x     = (const float*)d_in[0];
  const float* boxes = (const float*)d_in[1];
  const float* w51   = (const float*)d_in[2];
  const float* b51   = (const float*)d_in[3];
  const float* w15   = (const float*)d_in[4];
  const float* b15   = (const float*)d_in[5];
  const float* w11   = (const float*)d_in[6];
  const float* b11   = (const float*)d_in[7];
  float* out = (float*)d_out;

  __hip_bfloat16* featT = (__hip_bfloat16*)d_ws;
  __hip_bfloat16* xT   = featT + (size_t)P_ * C_;
  __hip_bfloat16* w1t  = xT + (size_t)P_ * C_;
  __hip_bfloat16* w2t  = w1t + (size_t)C_ * 1280;
  __hip_bfloat16* zbuf = w2t + (size_t)C_ * 1536;
  __hip_bfloat16* t1 = (__hip_bfloat16*)d_out;

  wtrans_kernel<<<dim3((C_ * C_ * 5 + 255) / 256), 256, 0, stream>>>(
      w15, w51, w11, w1t, w2t, zbuf);
  nchw2nhwc_kernel<<<dim3(HW_ / 32, C_ / 32, B_), dim3(32, 8), 0, stream>>>(x, xT);
  gemm1_kernel<<<dim3(768), 256, 0, stream>>>(xT, w1t, b15, t1, zbuf);
  gemm2_kernel<<<dim3(768), 256, 0, stream>>>(t1, xT, w2t, b51, b11, featT, zbuf);
  align_kernel<<<dim3(P_ / 16), 256, 0, stream>>>(xT, featT, boxes, out);
}

// Round 10
// 172.019 us; speedup vs baseline: 1.0584x; 1.0039x over previous
//
#include <hip/hip_runtime.h>
#include <hip/hip_bf16.h>
#include <stdint.h>

#define B_ 2
#define C_ 256
#define H_ 192
#define W_ 192
#define HW_ (H_*W_)
#define CHW_ (C_*HW_)
#define P_ (B_*HW_)
#define SCALE 0.125f

typedef __attribute__((ext_vector_type(8))) short bf16x8;
typedef __attribute__((ext_vector_type(4))) float f32x4;

__device__ __forceinline__ void gload_lds16(const void* g, void* l) {
  __builtin_amdgcn_global_load_lds(
      (const __attribute__((address_space(1))) uint32_t*)g,
      (__attribute__((address_space(3))) uint32_t*)l, 16, 0, 0);
}

// ---- weights: w15/w51 [co][ci][k] fp32 -> bf16 [co][k*256+ci]; w11 appended; zero zbuf
__global__ __launch_bounds__(256) void wtrans_kernel(
    const float* __restrict__ w15, const float* __restrict__ w51,
    const float* __restrict__ w11,
    __hip_bfloat16* __restrict__ w1t, __hip_bfloat16* __restrict__ w2t,
    __hip_bfloat16* __restrict__ zbuf) {
  int i = blockIdx.x * 256 + threadIdx.x;
  if (i < C_ * C_ * 5) {
    int co = i / (C_ * 5);
    int r  = i - co * (C_ * 5);
    int ci = r / 5;
    int k  = r - ci * 5;
    w1t[(size_t)co * 1280 + k * 256 + ci] = __float2bfloat16(w15[i]);
    w2t[(size_t)co * 1536 + k * 256 + ci] = __float2bfloat16(w51[i]);
  }
  if (i < C_ * C_) {
    int co = i >> 8, ci = i & 255;
    w2t[(size_t)co * 1536 + 1280 + ci] = __float2bfloat16(w11[i]);
  }
  if (i < 1024) zbuf[i] = __float2bfloat16(0.f);
}

// ---- x NCHW fp32 -> xT NHWC bf16. 64x64 tile, float4 reads, 32B bf16 writes.
__global__ __launch_bounds__(256) void nchw2nhwc_kernel(
    const float* __restrict__ x, __hip_bfloat16* __restrict__ xT) {
  __shared__ float tile[64][65];  // [c][p], 65-pad: 2-way max on both phases
  const int p0 = blockIdx.x * 64, c0 = blockIdx.y * 64, b = blockIdx.z;
  const int tid = threadIdx.x;
  const float* xb = x + (size_t)b * CHW_;
  {
    const int cr = tid >> 4;       // 0..15
    const int pc = (tid & 15) * 4; // 0..60
#pragma unroll
    for (int j = 0; j < 4; ++j) {
      float4 v = *(const float4*)(xb + (size_t)(c0 + cr + j * 16) * HW_ + p0 + pc);
      *(float4*)&tile[cr + j * 16][pc] = v;
    }
  }
  __syncthreads();
  {
    const int pr = tid >> 2;        // 0..63 pixel row
    const int cc = (tid & 3) * 16;  // 16-ch chunk
    union { unsigned short u[16]; uint4 q[2]; } wpk;
#pragma unroll
    for (int j = 0; j < 16; ++j) {
      __hip_bfloat16 hb = __float2bfloat16(tile[cc + j][pr]);
      wpk.u[j] = *(unsigned short*)&hb;
    }
    char* xo = (char*)(xT + ((size_t)b * HW_ + p0 + pr) * C_ + c0 + cc);
    *(uint4*)xo = wpk.q[0];
    *(uint4*)(xo + 16) = wpk.q[1];
  }
}

// ---- GEMM1 (frozen): t1[p][co] = bf16(conv1x5(xT)+b15). Tile = one h-row x 128 co.
#define AB1 25600  // A = 200 rows * 128B
__global__ __launch_bounds__(256, 3) void gemm1_kernel(
    const __hip_bfloat16* __restrict__ xT, const __hip_bfloat16* __restrict__ w1t,
    const float* __restrict__ b15, __hip_bfloat16* __restrict__ t1,
    const __hip_bfloat16* __restrict__ zbuf) {
  __shared__ __align__(16) char lds[AB1 + 16384];
  int bid = blockIdx.x;
  bid = (bid & 7) * 96 + (bid >> 3);  // XCD swizzle (768 % 8 == 0)
  const int nb = bid & 1, bh = bid >> 1;
  const int p0 = bh * 192;
  const int tid = threadIdx.x, l = tid & 63, wid = tid >> 6;
  const int wrow = (wid >> 1) * 96, wcol = (wid & 1) * 64;
  const int sboff = (((l & 7) ^ (l >> 3)) << 4);
  const int lrow = l >> 3;
  const int corow0 = nb * 128;

  int b_ad[4][2];
#pragma unroll
  for (int n = 0; n < 4; ++n)
#pragma unroll
    for (int kk = 0; kk < 2; ++kk)
      b_ad[n][kk] = AB1 + (wcol + n * 16 + (l & 15)) * 128 +
                    (((kk * 4 + (l >> 4)) ^ ((l & 15) & 7)) << 4);

  f32x4 acc[6][4] = {};
  const char* xTb = (const char*)xT;
  const char* wB  = (const char*)w1t;
  const char* zb  = (const char*)zbuf;

  for (int cib = 0; cib < 4; ++cib) {
    for (int is = wid; is < 25; is += 4) {
      int row = is * 8 + lrow;
      const char* src = ((unsigned)(row - 4) < 192u)
          ? xTb + (size_t)(p0 + row - 4) * 512 + cib * 128 + sboff
          : zb + sboff;
      gload_lds16(src, lds + is * 1024);
    }
    for (int k = 0; k < 5; ++k) {
      int boff = k * 512 + cib * 128;
#pragma unroll
      for (int ii = 0; ii < 4; ++ii) {
        int is = wid * 4 + ii;
        const char* bs = wB + (size_t)(corow0 + is * 8 + lrow) * 2560 + boff + sboff;
        gload_lds16(bs, lds + AB1 + is * 1024);
      }
      __syncthreads();
      int x8 = ((l & 15) + k + 2) & 7;
      int arow0 = wrow + (l & 15) + k + 2;
#pragma unroll
      for (int kk = 0; kk < 2; ++kk) {
        int ablk = ((kk * 4 + (l >> 4)) ^ x8) << 4;
        bf16x8 bfr[4];
#pragma unroll
        for (int n = 0; n < 4; ++n) bfr[n] = *(const bf16x8*)(lds + b_ad[n][kk]);
#pragma unroll
        for (int m = 0; m < 6; ++m) {
          bf16x8 af = *(const bf16x8*)(lds + (arow0 + m * 16) * 128 + ablk);
#pragma unroll
          for (int n = 0; n < 4; ++n)
            acc[m][n] = __builtin_amdgcn_mfma_f32_16x16x32_bf16(af, bfr[n], acc[m][n], 0, 0, 0);
        }
      }
      __syncthreads();
    }
  }
#pragma unroll
  for (int n = 0; n < 4; ++n) {
    int co = corow0 + wcol + n * 16 + (l & 15);
    float bias = b15[co];
#pragma unroll
    for (int m = 0; m < 6; ++m) {
      int prow = p0 + wrow + m * 16 + (l >> 4) * 4;
#pragma unroll
      for (int r = 0; r < 4; ++r)
        t1[(size_t)(prow + r) * 256 + co] = __float2bfloat16(acc[m][n][r] + bias);
    }
  }
}

// ---- GEMM2 (frozen, R5 winner): 16x16x32, 96x64 wave tile, 2-barrier loop.
#define AB2 24576  // A = 192 rows * 128B
__global__ __launch_bounds__(256, 3) void gemm2_kernel(
    const __hip_bfloat16* __restrict__ t1, const __hip_bfloat16* __restrict__ xT,
    const __hip_bfloat16* __restrict__ w2t,
    const float* __restrict__ b51, const float* __restrict__ b11,
    __hip_bfloat16* __restrict__ featT, const __hip_bfloat16* __restrict__ zbuf) {
  __shared__ __align__(16) char lds[AB2 + 16384];
  int bid = blockIdx.x;
  bid = (bid & 7) * 96 + (bid >> 3);
  const int nb = bid & 1, bh = bid >> 1;
  const int p0 = bh * 192;
  const int h = bh % 192;
  const int tid = threadIdx.x, l = tid & 63, wid = tid >> 6;
  const int wrow = (wid >> 1) * 96, wcol = (wid & 1) * 64;
  const int sboff = (((l & 7) ^ (l >> 3)) << 4);
  const int lrow = l >> 3;
  const int corow0 = nb * 128;

  int a_ad[6][2], b_ad[4][2];
#pragma unroll
  for (int m = 0; m < 6; ++m)
#pragma unroll
    for (int kk = 0; kk < 2; ++kk)
      a_ad[m][kk] = (wrow + m * 16 + (l & 15)) * 128 +
                    (((kk * 4 + (l >> 4)) ^ ((l & 15) & 7)) << 4);
#pragma unroll
  for (int n = 0; n < 4; ++n)
#pragma unroll
    for (int kk = 0; kk < 2; ++kk)
      b_ad[n][kk] = AB2 + (wcol + n * 16 + (l & 15)) * 128 +
                    (((kk * 4 + (l >> 4)) ^ ((l & 15) & 7)) << 4);

  f32x4 acc[6][4] = {};
  const char* t1b = (const char*)t1;
  const char* xTb = (const char*)xT;
  const char* wB  = (const char*)w2t;
  const char* zb  = (const char*)zbuf;

  for (int s = 0; s < 24; ++s) {
    const char* abase;
    int boff;
    if (s < 20) {
      int k = s >> 2, cib = s & 3, dl = k - 2;
      abase = ((unsigned)(h + dl) < 192u)
          ? t1b + (size_t)(p0 + dl * 192) * 512 + cib * 128
          : (const char*)0;
      boff = k * 512 + cib * 128;
    } else {
      abase = xTb + (size_t)p0 * 512 + (s - 20) * 128;
      boff = 2560 + (s - 20) * 128;
    }
    for (int is = wid; is < 24; is += 4) {
      int row = is * 8 + lrow;
      const char* src = abase ? abase + (size_t)row * 512 + sboff : zb + sboff;
      gload_lds16(src, lds + is * 1024);
    }
#pragma unroll
    for (int ii = 0; ii < 4; ++ii) {
      int is = wid * 4 + ii;
      const char* bs = wB + (size_t)(corow0 + is * 8 + lrow) * 3072 + boff + sboff;
      gload_lds16(bs, lds + AB2 + is * 1024);
    }
    __syncthreads();
#pragma unroll
    for (int kk = 0; kk < 2; ++kk) {
      bf16x8 bfr[4];
#pragma unroll
      for (int n = 0; n < 4; ++n) bfr[n] = *(const bf16x8*)(lds + b_ad[n][kk]);
#pragma unroll
      for (int m = 0; m < 6; ++m) {
        bf16x8 af = *(const bf16x8*)(lds + a_ad[m][kk]);
#pragma unroll
        for (int n = 0; n < 4; ++n)
          acc[m][n] = __builtin_amdgcn_mfma_f32_16x16x32_bf16(af, bfr[n], acc[m][n], 0, 0, 0);
      }
    }
    __syncthreads();
  }
#pragma unroll
  for (int n = 0; n < 4; ++n) {
    int co = corow0 + wcol + n * 16 + (l & 15);
    float bias = b51[co] + b11[co];
#pragma unroll
    for (int m = 0; m < 6; ++m) {
      int prow = p0 + wrow + m * 16 + (l >> 4) * 4;
#pragma unroll
      for (int r = 0; r < 4; ++r)
        featT[(size_t)(prow + r) * 256 + co] = __float2bfloat16(acc[m][n][r] + bias);
    }
  }
}

// ---- out = x + feat + bilinear_gather(feat).
// Phase A: 2 pixels per wave-pass, 16B/lane uint4 gathers (32 lanes cover a
// 512B corner row). Phase B: lane=pixel, coalesced NCHW NT stores.
__global__ __launch_bounds__(256) void align_kernel(
    const __hip_bfloat16* __restrict__ xT, const __hip_bfloat16* __restrict__ featT,
    const float* __restrict__ boxes, float* __restrict__ out) {
  __shared__ float vs[16][258];  // [pixel][channel], +2 pad
  const int tid = threadIdx.x, l = tid & 63, wv = tid >> 6;
  const int p0 = blockIdx.x * 16;

#pragma unroll
  for (int i = 0; i < 2; ++i) {
    int pl = wv * 4 + i * 2 + (l >> 5);  // 2 px per pass, lanes 0-31 / 32-63
    int p = p0 + pl;
    int b = p / HW_;
    int p2 = p - b * HW_;
    float yy = boxes[(size_t)p * 5 + 0] * SCALE;
    float xx = boxes[(size_t)p * 5 + 1] * SCALE;
    bool valid = (yy >= -1.0f) && (yy <= (float)H_) && (xx >= -1.0f) && (xx <= (float)W_);
    yy = fmaxf(yy, 0.f);
    xx = fmaxf(xx, 0.f);
    int yl = (int)floorf(yy), xl = (int)floorf(xx);
    int yh, xh;
    if (yl >= H_ - 1) { yl = H_ - 1; yh = H_ - 1; yy = (float)(H_ - 1); } else { yh = yl + 1; }
    if (xl >= W_ - 1) { xl = W_ - 1; xh = W_ - 1; xx = (float)(W_ - 1); } else { xh = xl + 1; }
    float ly = yy - (float)yl, lx = xx - (float)xl;
    float hy = 1.f - ly, hx = 1.f - lx;
    float q00 = hy * hx, q01 = hy * lx, q10 = ly * hx, q11 = ly * lx;
    if (!valid) { q00 = 0.f; q01 = 0.f; q10 = 0.f; q11 = 0.f; }
    const unsigned short* fT = (const unsigned short*)featT + (size_t)b * HW_ * C_;
    const unsigned short* xb = (const unsigned short*)xT + (size_t)b * HW_ * C_;
    int co = (l & 31) * 8;  // this lane's 8 channels
    uint4 A  = *(const uint4*)(fT + ((size_t)yl * W_ + xl) * C_ + co);
    uint4 Bv = *(const uint4*)(fT + ((size_t)yl * W_ + xh) * C_ + co);
    uint4 Cv = *(const uint4*)(fT + ((size_t)yh * W_ + xl) * C_ + co);
    uint4 D  = *(const uint4*)(fT + ((size_t)yh * W_ + xh) * C_ + co);
    uint4 E  = *(const uint4*)(fT + (size_t)p2 * C_ + co);
    uint4 X  = *(const uint4*)(xb + (size_t)p2 * C_ + co);
    float o[8];
#pragma unroll
    for (int w = 0; w < 4; ++w) {
      unsigned int aw = (&A.x)[w], bw = (&Bv.x)[w], cw = (&Cv.x)[w],
                   dw = (&D.x)[w], ew = (&E.x)[w], xw = (&X.x)[w];
      float a0 = __uint_as_float(aw << 16), a1 = __uint_as_float(aw & 0xffff0000u);
      float b0 = __uint_as_float(bw << 16), b1 = __uint_as_float(bw & 0xffff0000u);
      float c0 = __uint_as_float(cw << 16), c1 = __uint_as_float(cw & 0xffff0000u);
      float d0 = __uint_as_float(dw << 16), d1 = __uint_as_float(dw & 0xffff0000u);
      float e0 = __uint_as_float(ew << 16), e1 = __uint_as_float(ew & 0xffff0000u);
      float x0 = __uint_as_float(xw << 16), x1 = __uint_as_float(xw & 0xffff0000u);
      o[w * 2 + 0] = x0 + e0 + q00 * a0 + q01 * b0 + q10 * c0 + q11 * d0;
      o[w * 2 + 1] = x1 + e1 + q00 * a1 + q01 * b1 + q10 * c1 + q11 * d1;
    }
    *(float4*)&vs[pl][co]     = make_float4(o[0], o[1], o[2], o[3]);
    *(float4*)&vs[pl][co + 4] = make_float4(o[4], o[5], o[6], o[7]);
  }
  __syncthreads();

  // Phase B: lane=pixel (16 px), 16 ch-groups of 16
  const int pl = tid & 15, cg = tid >> 4;
  const int p = p0 + pl;
  const int b = p / HW_;
  const int p2 = p - b * HW_;
  float* oc = out + (size_t)b * CHW_ + p2;
#pragma unroll
  for (int j = 0; j < 16; ++j) {
    int ch = cg * 16 + j;
    __builtin_nontemporal_store(vs[pl][ch], &oc[(size_t)ch * HW_]);
  }
}

extern "C" void kernel_launch(void* const* d_in, const int* in_sizes, int n_in,
                              void* d_out, int out_size, void* d_ws, size_t ws_size,
                              hipStream_t stream) {
  const float* x     = (const float*)d_in[0];
  const float* boxes = (const float*)d_in[1];
  const float* w51   = (const float*)d_in[2];
  const float* b51   = (const float*)d_in[3];
  const float* w15   = (const float*)d_in[4];
  const float* b15   = (const float*)d_in[5];
  const float* w11   = (const float*)d_in[6];
  const float* b11   = (const float*)d_in[7];
  float* out = (float*)d_out;

  __hip_bfloat16* featT = (__hip_bfloat16*)d_ws;
  __hip_bfloat16* xT   = featT + (size_t)P_ * C_;
  __hip_bfloat16* w1t  = xT + (size_t)P_ * C_;
  __hip_bfloat16* w2t  = w1t + (size_t)C_ * 1280;
  __hip_bfloat16* zbuf = w2t + (size_t)C_ * 1536;
  __hip_bfloat16* t1 = (__hip_bfloat16*)d_out;

  wtrans_kernel<<<dim3((C_ * C_ * 5 + 255) / 256), 256, 0, stream>>>(
      w15, w51, w11, w1t, w2t, zbuf);
  nchw2nhwc_kernel<<<dim3(HW_ / 64, C_ / 64, B_), 256, 0, stream>>>(x, xT);
  gemm1_kernel<<<dim3(768), 256, 0, stream>>>(xT, w1t, b15, t1, zbuf);
  gemm2_kernel<<<dim3(768), 256, 0, stream>>>(t1, xT, w2t, b51, b11, featT, zbuf);
  align_kernel<<<dim3(P_ / 16), 256, 0, stream>>>(xT, featT, boxes, out);
}